// Round 6
// baseline (220.509 us; speedup 1.0000x reference)
//
#include <hip/hip_runtime.h>
#include <math.h>

#define BB 32
#define CCH 224
#define TTT 2048
#define TPB 128            // t per tile in kf
#define NT  (TTT/TPB)      // 16 tiles -> 18 phases
#define CG  28             // chains (channels) per kf block (halo-optimal)
#define NCG (CCH/CG)       // 8
#define IROW 29            // f64 per I row (28 + 1 pad)
#define CPW 4              // channels per conv thread (7 conv waves)

// LDS-only barrier: cross-wave deps in kf are all through LDS (Is, bitsb).
// Stores stay fire-and-forget; prefetch loads stay in flight across barriers.
__device__ __forceinline__ void bar_lds() {
    asm volatile("s_waitcnt lgkmcnt(0)" ::: "memory");
    __builtin_amdgcn_s_barrier();
    asm volatile("" ::: "memory");
}

// ---------------------------------------------------------------------------
// kw v3: per (b,t): f64 dot over C -> w -> 7 symmetric Gaussian taps (f64).
// 1024-thread blocks: 256 t x 4 channel-quarters; grid (8,32) = 256 blocks
// = 16 waves/CU. Tail (64-deep norm recurrence + exps) now runs on 256
// lanes/block (was 64) -> 4x tail parallelism. Summation order preserved
// exactly: p_q sequential over its 56 channels, (p0+p1)+(p2+p3).
// ---------------------------------------------------------------------------
__global__ __launch_bounds__(1024) void kw(
    const float* __restrict__ x, const float* __restrict__ lw,
    double* __restrict__ kernG)
{
    __shared__ double sp[4][256];
    const int b  = blockIdx.y;
    const int tl = threadIdx.x & 255;          // t within block tile
    const int q  = threadIdx.x >> 8;           // channel quarter 0..3
    const int t  = blockIdx.x * 256 + tl;

    const float* xb  = x + (((size_t)(b * CCH + 56 * q)) << 11) + t;
    const float* lwq = lw + 56 * q;

    double p = 0.0;
    #pragma unroll 8
    for (int i = 0; i < 56; ++i)
        p += (double)xb[(size_t)i << 11] * (double)lwq[i];
    sp[q][tl] = p;
    __syncthreads();

    if (threadIdx.x < 256) {
        const int tt = blockIdx.x * 256 + threadIdx.x;
        double acc = (sp[0][threadIdx.x] + sp[1][threadIdx.x])
                   + (sp[2][threadIdx.x] + sp[3][threadIdx.x]);

        double w = 5.2 + acc * 9.6;
        w = fmin(fmax(w, 0.4), 10.0);
        double iw2 = 1.0 / (w * w);

        // norm over linspace(-60,60,130): symmetric -> 2x half-sum,
        // terms G^{(2u+1)^2} via power recurrence (2 exps total)
        const double s = 120.0 / 129.0;
        double G  = exp(-0.125 * s * s * iw2);
        double G2 = G * G, G4 = G2 * G2, G8 = G4 * G4;
        double term = G, cmul = G8, norm = G;
        for (int u = 1; u <= 64; ++u) { term *= cmul; cmul *= G8; norm += term; }
        norm *= 2.0;

        double P = exp(-0.5 * iw2), P2 = P * P;
        double a = 1.0, bm = P, inv = 1.0 / norm;
        double* kr = kernG + (size_t)(b * TTT + tt) * 7;
        kr[0] = inv;                      // center tap
        #pragma unroll
        for (int d = 1; d <= 6; ++d) {
            a *= bm; bm *= P2;
            kr[d] = a * inv;              // tap at distance d (symmetric)
        }
    }
}

// ---------------------------------------------------------------------------
// kf v7: fused conv + LIF scan + spikes. grid (8,32) x 512 threads.
// Structure identical to verified v6 (reg-held x, 18 phases, LDS = Is+bitsb).
// Scan step rewritten to the minimum bit-exact chain:
//   m1 = fma(.95,mem,a); m2 = fma(.95,mem,a-1)   (parallel)
//   r1 = m1>1; r2 = m2>1                          (off the serial path)
//   mem = r ? m2 : m1                             (cycle A: fma+sel)
//   r   = r ? r2 : r1                             (1-bit blend -> SALU masks)
// vs previous r = (mem > 1): removes the f64 compare (and its VCC
// serialization) from the r-recurrence. Selection commutes with comparison
// -> bit-identical results.
// ---------------------------------------------------------------------------
__global__ __launch_bounds__(512) void kf(
    const float* __restrict__ x, const double* __restrict__ kernG,
    float* __restrict__ out)
{
    __shared__ double Is[2][TPB][IROW];                // 59392 B
    __shared__ unsigned long long bitsb[2][CG][2];     //   896 B

    const int b   = blockIdx.y;
    const int cgi = blockIdx.x;
    const int c0  = cgi * CG;
    const int tid = threadIdx.x;
    const int ctid = tid - 64;          // 0..447 for conv waves

    const float*  xbase = x + (((size_t)(b * CCH)) << 11);
    const double* kbase = kernG + (size_t)(b * TTT) * 7;
    float* obase = out + (((size_t)(b * CCH + c0)) << 11);

    double mem = 0.0;   // scan state (wave0 lanes)
    bool   r   = false;

    const int tl = ctid & 63;           // conv lane t within half
    const int g  = ctid >> 6;           // conv wave group 0..6
    const int cb = CPW * g;             // first channel (relative) of group

    // issue all global loads for one tile into a reg set (conv waves only)
    auto issue = [&](int tile, float (&rv)[2][16], double (&kv)[2][7]) {
        const int gt0 = tile * TPB;
        #pragma unroll
        for (int h = 0; h < 2; ++h) {
            const int tt = gt0 + tl + 64 * h;
            #pragma unroll
            for (int i = 0; i < 16; ++i) {
                int cr = c0 + cb - 6 + i;
                rv[h][i] = (cr >= 0 && cr < CCH)
                         ? xbase[((size_t)cr << 11) + tt] : 0.f;
            }
            const double* kp = kbase + (size_t)tt * 7;
            #pragma unroll
            for (int i = 0; i < 7; ++i) kv[h][i] = kp[i];
        }
    };

    auto phase = [&](int k, float (&rv)[2][16], double (&kv)[2][7]) {
        if (tid >= 64) {
            const int buf = k & 1;
            // (1) out-write(k-2): fire-and-forget coalesced float4 stores
            if (k >= 2) {
                const int j = k - 2, jb = j & 1;
                const int t0o = j * TPB;
                const int c = ctid >> 4, q = ctid & 15;
                #pragma unroll
                for (int h = 0; h < 2; ++h) {
                    unsigned long long bits = bitsb[jb][c][h] >> (4 * q);
                    float4 v;
                    v.x = (bits & 1ull) ? 1.0f : 0.0f;
                    v.y = (bits & 2ull) ? 1.0f : 0.0f;
                    v.z = (bits & 4ull) ? 1.0f : 0.0f;
                    v.w = (bits & 8ull) ? 1.0f : 0.0f;
                    *(float4*)(obase + ((size_t)c << 11) + t0o + 64 * h + 4 * q) = v;
                }
            }
            // (2) conv(k): registers -> Is[buf]; two t-halves sequentially
            if (k <= NT - 1) {
                #pragma unroll
                for (int h = 0; h < 2; ++h) {
                    double kk7[7];
                    #pragma unroll
                    for (int i = 0; i < 7; ++i) kk7[i] = kv[h][i];
                    double xv[16];
                    #pragma unroll
                    for (int i = 0; i < 16; ++i) xv[i] = (double)rv[h][i];
                    #pragma unroll
                    for (int c = 0; c < CPW; ++c) {
                        double acc = 0.0;
                        #pragma unroll
                        for (int kk = 0; kk < 13; ++kk) {
                            int d = kk < 6 ? 6 - kk : kk - 6;
                            acc = fma(xv[c + kk], kk7[d], acc);
                        }
                        double xvv = xv[c + 6];
                        double dd  = xvv - acc;
                        Is[buf][tl + 64 * h][cb + c] = xvv - (dd > 0.0 ? dd : 0.0);
                    }
                }
            }
            // (3) issue loads for tile k+2 (land during phase k+1, used k+2)
            if (k + 2 <= NT - 1) issue(k + 2, rv, kv);
        } else {
            // scan(k-1): 128 LIF steps, min-chain step, 8-deep prefetch
            if (k >= 1 && k <= NT) {
                const int p = (k - 1) & 1;
                const int c = tid;
                __builtin_amdgcn_s_setprio(1);
                if (c < CG) {
                    unsigned long long bits0 = 0ull, bits1 = 0ull;
                    double va[8], vb8[8], ca[8], cb2[8];
                    #pragma unroll
                    for (int j2 = 0; j2 < 8; ++j2) va[j2] = Is[p][j2][c];
                    #pragma unroll
                    for (int j2 = 0; j2 < 8; ++j2) ca[j2] = va[j2] - 1.0;
                    for (int g2 = 0; g2 < TPB; g2 += 16) {
                        #pragma unroll
                        for (int j2 = 0; j2 < 8; ++j2) vb8[j2] = Is[p][g2 + 8 + j2][c];
                        #pragma unroll
                        for (int j2 = 0; j2 < 8; ++j2) cb2[j2] = vb8[j2] - 1.0;
                        #pragma unroll
                        for (int j2 = 0; j2 < 8; ++j2) {
                            double m1 = fma(0.95, mem, va[j2]);
                            double m2 = fma(0.95, mem, ca[j2]);
                            bool r1 = m1 > 1.0;
                            bool r2 = m2 > 1.0;
                            bool rn = r ? r2 : r1;
                            mem = r ? m2 : m1;
                            r = rn;
                            const int s = g2 + j2;
                            unsigned long long bb =
                                (unsigned long long)(r ? 1 : 0) << (s & 63);
                            if (s < 64) bits0 |= bb; else bits1 |= bb;
                        }
                        if (g2 + 16 < TPB) {
                            #pragma unroll
                            for (int j2 = 0; j2 < 8; ++j2) va[j2] = Is[p][g2 + 16 + j2][c];
                            #pragma unroll
                            for (int j2 = 0; j2 < 8; ++j2) ca[j2] = va[j2] - 1.0;
                        }
                        #pragma unroll
                        for (int j2 = 0; j2 < 8; ++j2) {
                            double m1 = fma(0.95, mem, vb8[j2]);
                            double m2 = fma(0.95, mem, cb2[j2]);
                            bool r1 = m1 > 1.0;
                            bool r2 = m2 > 1.0;
                            bool rn = r ? r2 : r1;
                            mem = r ? m2 : m1;
                            r = rn;
                            const int s = g2 + 8 + j2;
                            unsigned long long bb =
                                (unsigned long long)(r ? 1 : 0) << (s & 63);
                            if (s < 64) bits0 |= bb; else bits1 |= bb;
                        }
                    }
                    bitsb[p][c][0] = bits0;
                    bitsb[p][c][1] = bits1;
                }
                __builtin_amdgcn_s_setprio(0);
            }
        }
        bar_lds();
    };

    // ping-pong register sets (statically indexed — rule #20)
    float  rA[2][16], rB[2][16];
    double kA[2][7],  kB[2][7];

    // prologue: issue tiles 0 (set A) and 1 (set B)
    if (tid >= 64) {
        issue(0, rA, kA);
        issue(1, rB, kB);
    }

    // 18 phases, unrolled by 2 so reg-set parity is static
    for (int kk = 0; kk < NT + 2; kk += 2) {
        phase(kk,     rA, kA);
        phase(kk + 1, rB, kB);
    }
}

// ---------------------------------------------------------------------------
extern "C" void kernel_launch(void* const* d_in, const int* in_sizes, int n_in,
                              void* d_out, int out_size, void* d_ws, size_t ws_size,
                              hipStream_t stream)
{
    const float* x  = (const float*)d_in[0];   // (32,1,224,2048) f32
    const float* lw = (const float*)d_in[1];   // (1,224) f32
    float* out = (float*)d_out;                // (32,1,224,2048) f32

    double* kernG = (double*)d_ws;             // 65536 * 7 * 8 = 3,670,016 B

    kw<<<dim3(TTT / 256, BB), 1024, 0, stream>>>(x, lw, kernG);
    kf<<<dim3(NCG, BB), 512, 0, stream>>>(x, kernG, out);
}

// Round 8
// 177.805 us; speedup vs baseline: 1.2402x; 1.2402x over previous
//
#include <hip/hip_runtime.h>
#include <math.h>

#define BB 32
#define CCH 224
#define TTT 2048
#define TPB 128            // t per tile in kf
#define NT  (TTT/TPB)      // 16 tiles -> 18 phases
#define CG  28             // chains (channels) per kf block (halo-optimal)
#define NCG (CCH/CG)       // 8
#define IROW 29            // f64 per I row (28 + 1 pad)
#define CPW 4              // channels per conv thread (7 conv waves)

// LDS-only barrier: cross-wave deps in kf are all through LDS (Is, bitsb).
// Stores stay fire-and-forget; prefetch loads stay in flight across barriers.
__device__ __forceinline__ void bar_lds() {
    asm volatile("s_waitcnt lgkmcnt(0)" ::: "memory");
    __builtin_amdgcn_s_barrier();
    asm volatile("" ::: "memory");
}

// ---------------------------------------------------------------------------
// kw v3: per (b,t): f64 dot over C -> w -> 7 symmetric Gaussian taps (f64).
// 1024-thread blocks: 256 t x 4 channel-quarters; grid (8,32).
// Summation order preserved exactly: p_q sequential, (p0+p1)+(p2+p3).
// ---------------------------------------------------------------------------
__global__ __launch_bounds__(1024) void kw(
    const float* __restrict__ x, const float* __restrict__ lw,
    double* __restrict__ kernG)
{
    __shared__ double sp[4][256];
    const int b  = blockIdx.y;
    const int tl = threadIdx.x & 255;          // t within block tile
    const int q  = threadIdx.x >> 8;           // channel quarter 0..3
    const int t  = blockIdx.x * 256 + tl;

    const float* xb  = x + (((size_t)(b * CCH + 56 * q)) << 11) + t;
    const float* lwq = lw + 56 * q;

    double p = 0.0;
    #pragma unroll 8
    for (int i = 0; i < 56; ++i)
        p += (double)xb[(size_t)i << 11] * (double)lwq[i];
    sp[q][tl] = p;
    __syncthreads();

    if (threadIdx.x < 256) {
        const int tt = blockIdx.x * 256 + threadIdx.x;
        double acc = (sp[0][threadIdx.x] + sp[1][threadIdx.x])
                   + (sp[2][threadIdx.x] + sp[3][threadIdx.x]);

        double w = 5.2 + acc * 9.6;
        w = fmin(fmax(w, 0.4), 10.0);
        double iw2 = 1.0 / (w * w);

        // norm over linspace(-60,60,130): symmetric -> 2x half-sum,
        // terms G^{(2u+1)^2} via power recurrence (2 exps total)
        const double s = 120.0 / 129.0;
        double G  = exp(-0.125 * s * s * iw2);
        double G2 = G * G, G4 = G2 * G2, G8 = G4 * G4;
        double term = G, cmul = G8, norm = G;
        for (int u = 1; u <= 64; ++u) { term *= cmul; cmul *= G8; norm += term; }
        norm *= 2.0;

        double P = exp(-0.5 * iw2), P2 = P * P;
        double a = 1.0, bm = P, inv = 1.0 / norm;
        double* kr = kernG + (size_t)(b * TTT + tt) * 7;
        kr[0] = inv;                      // center tap
        #pragma unroll
        for (int d = 1; d <= 6; ++d) {
            a *= bm; bm *= P2;
            kr[d] = a * inv;              // tap at distance d (symmetric)
        }
    }
}

// ---------------------------------------------------------------------------
// kf v8: fused conv + LIF scan + spikes. grid (8,32) x 512 threads.
// Structure identical to verified v6 (reg-held x, 18 phases, LDS = Is+bitsb).
// Scan: 2-step SPECULATIVE LIF. Per step-pair, all 4 candidate mems and both
// candidate predicates are computed in parallel (off the serial cycle); the
// serial cycle is cmp -> mask-blend -> cndmask -> cndmask (~4 dep-ops / 2
// steps vs 8 before). NO carried bool (r6 lesson: named carried predicates
// get materialized to VGPR and re-converted, doubling the chain) — the
// carried state is only {mem}; predicates are consumed immediately.
// Selected path executes the identical fma sequence as sequential execution
// (ca = a-1.0 precomputed off-chain, single fma per step) -> bit-identical.
// ---------------------------------------------------------------------------
__global__ __launch_bounds__(512) void kf(
    const float* __restrict__ x, const double* __restrict__ kernG,
    float* __restrict__ out)
{
    __shared__ double Is[2][TPB][IROW];                // 59392 B
    __shared__ unsigned long long bitsb[2][CG][2];     //   896 B

    const int b   = blockIdx.y;
    const int cgi = blockIdx.x;
    const int c0  = cgi * CG;
    const int tid = threadIdx.x;
    const int ctid = tid - 64;          // 0..447 for conv waves

    const float*  xbase = x + (((size_t)(b * CCH)) << 11);
    const double* kbase = kernG + (size_t)(b * TTT) * 7;
    float* obase = out + (((size_t)(b * CCH + c0)) << 11);

    double mem = 0.0;   // scan state (wave0 lanes); initial mem=0 -> p=false

    const int tl = ctid & 63;           // conv lane t within half
    const int g  = ctid >> 6;           // conv wave group 0..6
    const int cb = CPW * g;             // first channel (relative) of group

    // issue all global loads for one tile into a reg set (conv waves only)
    auto issue = [&](int tile, float (&rv)[2][16], double (&kv)[2][7]) {
        const int gt0 = tile * TPB;
        #pragma unroll
        for (int h = 0; h < 2; ++h) {
            const int tt = gt0 + tl + 64 * h;
            #pragma unroll
            for (int i = 0; i < 16; ++i) {
                int cr = c0 + cb - 6 + i;
                rv[h][i] = (cr >= 0 && cr < CCH)
                         ? xbase[((size_t)cr << 11) + tt] : 0.f;
            }
            const double* kp = kbase + (size_t)tt * 7;
            #pragma unroll
            for (int i = 0; i < 7; ++i) kv[h][i] = kp[i];
        }
    };

    // 2-step speculative LIF: advances mem by two steps, returns the two
    // spike bits via out-params. All predicates inline (vcc-resident).
    auto lif2 = [&](double a0, double c0d, double a1, double c1d,
                    unsigned long long& bo0, unsigned long long& bo1) {
        const double mA  = fma(0.95, mem, a0);     // mem_j candidates
        const double mB  = fma(0.95, mem, c0d);
        const double mAA = fma(0.95, mA, a1);      // mem_{j+1} candidates
        const double mAB = fma(0.95, mA, c1d);
        const double mBA = fma(0.95, mB, a1);
        const double mBB = fma(0.95, mB, c1d);
        const bool p  = mem > 1.0;                 // pred entering step j
        const bool pA = mA > 1.0;
        const bool pB = mB > 1.0;
        const bool p1 = p ? pB : pA;               // pred after step j (mask blend)
        const double x1 = p1 ? mAB : mAA;
        const double y1 = p1 ? mBB : mBA;
        mem = p ? y1 : x1;                         // mem after step j+1
        bo0 = p1 ? 1ull : 0ull;                    // spike bit of step j
        bo1 = (mem > 1.0) ? 1ull : 0ull;           // spike bit of step j+1
    };

    auto phase = [&](int k, float (&rv)[2][16], double (&kv)[2][7]) {
        if (tid >= 64) {
            const int buf = k & 1;
            // (1) out-write(k-2): fire-and-forget coalesced float4 stores
            if (k >= 2) {
                const int j = k - 2, jb = j & 1;
                const int t0o = j * TPB;
                const int c = ctid >> 4, q = ctid & 15;
                #pragma unroll
                for (int h = 0; h < 2; ++h) {
                    unsigned long long bits = bitsb[jb][c][h] >> (4 * q);
                    float4 v;
                    v.x = (bits & 1ull) ? 1.0f : 0.0f;
                    v.y = (bits & 2ull) ? 1.0f : 0.0f;
                    v.z = (bits & 4ull) ? 1.0f : 0.0f;
                    v.w = (bits & 8ull) ? 1.0f : 0.0f;
                    *(float4*)(obase + ((size_t)c << 11) + t0o + 64 * h + 4 * q) = v;
                }
            }
            // (2) conv(k): registers -> Is[buf]; two t-halves sequentially
            if (k <= NT - 1) {
                #pragma unroll
                for (int h = 0; h < 2; ++h) {
                    double kk7[7];
                    #pragma unroll
                    for (int i = 0; i < 7; ++i) kk7[i] = kv[h][i];
                    double xv[16];
                    #pragma unroll
                    for (int i = 0; i < 16; ++i) xv[i] = (double)rv[h][i];
                    #pragma unroll
                    for (int c = 0; c < CPW; ++c) {
                        double acc = 0.0;
                        #pragma unroll
                        for (int kk = 0; kk < 13; ++kk) {
                            int d = kk < 6 ? 6 - kk : kk - 6;
                            acc = fma(xv[c + kk], kk7[d], acc);
                        }
                        double xvv = xv[c + 6];
                        double dd  = xvv - acc;
                        Is[buf][tl + 64 * h][cb + c] = xvv - (dd > 0.0 ? dd : 0.0);
                    }
                }
            }
            // (3) issue loads for tile k+2 (land during phase k+1, used k+2)
            if (k + 2 <= NT - 1) issue(k + 2, rv, kv);
        } else {
            // scan(k-1): 128 LIF steps via 2-step speculation, 8-deep prefetch
            if (k >= 1 && k <= NT) {
                const int p = (k - 1) & 1;
                const int c = tid;
                __builtin_amdgcn_s_setprio(1);
                if (c < CG) {
                    unsigned long long bits0 = 0ull, bits1 = 0ull;
                    double va[8], vb8[8], ca[8], cb2[8];
                    #pragma unroll
                    for (int j2 = 0; j2 < 8; ++j2) va[j2] = Is[p][j2][c];
                    #pragma unroll
                    for (int j2 = 0; j2 < 8; ++j2) ca[j2] = va[j2] - 1.0;
                    for (int g2 = 0; g2 < TPB; g2 += 16) {
                        #pragma unroll
                        for (int j2 = 0; j2 < 8; ++j2) vb8[j2] = Is[p][g2 + 8 + j2][c];
                        #pragma unroll
                        for (int j2 = 0; j2 < 8; ++j2) cb2[j2] = vb8[j2] - 1.0;
                        #pragma unroll
                        for (int j2 = 0; j2 < 8; j2 += 2) {
                            unsigned long long b0, b1;
                            lif2(va[j2], ca[j2], va[j2 + 1], ca[j2 + 1], b0, b1);
                            const int s = g2 + j2;    // subgroup entirely <64 or >=64
                            if (s < 64) bits0 |= (b0 << s) | (b1 << (s + 1));
                            else        bits1 |= (b0 << (s - 64)) | (b1 << (s - 63));
                        }
                        if (g2 + 16 < TPB) {
                            #pragma unroll
                            for (int j2 = 0; j2 < 8; ++j2) va[j2] = Is[p][g2 + 16 + j2][c];
                            #pragma unroll
                            for (int j2 = 0; j2 < 8; ++j2) ca[j2] = va[j2] - 1.0;
                        }
                        #pragma unroll
                        for (int j2 = 0; j2 < 8; j2 += 2) {
                            unsigned long long b0, b1;
                            lif2(vb8[j2], cb2[j2], vb8[j2 + 1], cb2[j2 + 1], b0, b1);
                            const int s = g2 + 8 + j2;
                            if (s < 64) bits0 |= (b0 << s) | (b1 << (s + 1));
                            else        bits1 |= (b0 << (s - 64)) | (b1 << (s - 63));
                        }
                    }
                    bitsb[p][c][0] = bits0;
                    bitsb[p][c][1] = bits1;
                }
                __builtin_amdgcn_s_setprio(0);
            }
        }
        bar_lds();
    };

    // ping-pong register sets (statically indexed — rule #20)
    float  rA[2][16], rB[2][16];
    double kA[2][7],  kB[2][7];

    // prologue: issue tiles 0 (set A) and 1 (set B)
    if (tid >= 64) {
        issue(0, rA, kA);
        issue(1, rB, kB);
    }

    // 18 phases, unrolled by 2 so reg-set parity is static
    for (int kk = 0; kk < NT + 2; kk += 2) {
        phase(kk,     rA, kA);
        phase(kk + 1, rB, kB);
    }
}

// ---------------------------------------------------------------------------
extern "C" void kernel_launch(void* const* d_in, const int* in_sizes, int n_in,
                              void* d_out, int out_size, void* d_ws, size_t ws_size,
                              hipStream_t stream)
{
    const float* x  = (const float*)d_in[0];   // (32,1,224,2048) f32
    const float* lw = (const float*)d_in[1];   // (1,224) f32
    float* out = (float*)d_out;                // (32,1,224,2048) f32

    double* kernG = (double*)d_ws;             // 65536 * 7 * 8 = 3,670,016 B

    kw<<<dim3(TTT / 256, BB), 1024, 0, stream>>>(x, lw, kernG);
    kf<<<dim3(NCG, BB), 512, 0, stream>>>(x, kernG, out);
}